// Round 8
// baseline (284.940 us; speedup 1.0000x reference)
//
#include <hip/hip_runtime.h>
#include <math.h>

typedef short bf16x8 __attribute__((ext_vector_type(8)));
typedef float f32x4  __attribute__((ext_vector_type(4)));
typedef float f32x2  __attribute__((ext_vector_type(2)));
typedef unsigned short u16;
typedef unsigned int   u32;

#define MFMA16 __builtin_amdgcn_mfma_f32_16x16x32_bf16

__device__ __forceinline__ u16 f2b(float x) {   // fp32 -> bf16 RNE
    union { float f; unsigned u; } v; v.f = x;
    unsigned r = v.u + 0x7fffu + ((v.u >> 16) & 1u);
    return (u16)(r >> 16);
}
// round-half-up bf16 (2 VALU vs 4; <=0.5ulp) — Xhat/O1 quantization
__device__ __forceinline__ u16 f2bu(float x) {
    union { float f; unsigned u; } v; v.f = x;
    return (u16)((v.u + 0x8000u) >> 16);
}
__device__ __forceinline__ float b2f(u16 h) {
    union { unsigned u; float f; } v; v.u = ((unsigned)h) << 16;
    return v.f;
}
__device__ __forceinline__ float blo(u32 w) {
    union { u32 u; float f; } v; v.u = w << 16; return v.f;
}
__device__ __forceinline__ float bhi(u32 w) {
    union { u32 u; float f; } v; v.u = w & 0xffff0000u; return v.f;
}
// sum 3 packed bf16 pairs in fp32 (order i0+i1+i2), repack bf16 HALF-UP via
// one v_perm_b32 (R14-verified). gather_stats' exp and mfma's recomputed
// A-frags use the IDENTICAL per-element op order -> bit-identical values.
__device__ __forceinline__ u32 add3pack(u32 x, u32 y, u32 z) {
    union { float f; u32 u; } lo, hi;
    lo.f = blo(x) + blo(y) + blo(z);
    hi.f = bhi(x) + bhi(y) + bhi(z);
    return __builtin_amdgcn_perm(hi.u + 0x8000u, lo.u + 0x8000u, 0x07060302u);
}
// packed f32 add (VOP3P v_pk_add_f32): 2 independent fp32 adds, 1 instr.
__device__ __forceinline__ f32x2 pk_add(f32x2 a, f32x2 b) {
    f32x2 d;
    asm("v_pk_add_f32 %0, %1, %2" : "=v"(d) : "v"(a), "v"(b));
    return d;
}
// add3pack on TWO packed u32 at once via v_pk_add_f32 (R19, measured-safe).
// Per-element op order (x+y)+z in fp32 — identical bits to scalar add3pack.
__device__ __forceinline__ void add3pack2(u32 x0, u32 x1, u32 y0, u32 y1,
                                          u32 z0, u32 z1, u32& d0, u32& d1) {
    union { f32x2 f; u32 u[2]; } lx, hx, ly, hy, lz, hz, lo, hi;
    lx.u[0] = x0 << 16;          lx.u[1] = x1 << 16;
    hx.u[0] = x0 & 0xffff0000u;  hx.u[1] = x1 & 0xffff0000u;
    ly.u[0] = y0 << 16;          ly.u[1] = y1 << 16;
    hy.u[0] = y0 & 0xffff0000u;  hy.u[1] = y1 & 0xffff0000u;
    lz.u[0] = z0 << 16;          lz.u[1] = z1 << 16;
    hz.u[0] = z0 & 0xffff0000u;  hz.u[1] = z1 & 0xffff0000u;
    lo.f = pk_add(pk_add(lx.f, ly.f), lz.f);
    hi.f = pk_add(pk_add(hx.f, hy.f), hz.f);
    d0 = __builtin_amdgcn_perm(hi.u[0] + 0x8000u, lo.u[0] + 0x8000u, 0x07060302u);
    d1 = __builtin_amdgcn_perm(hi.u[1] + 0x8000u, lo.u[1] + 0x8000u, 0x07060302u);
}
// pack 2 fp32 -> 2 bf16 half-up in one u32 (low u16 = f2bu(lo), hi = f2bu(hi))
__device__ __forceinline__ u32 pack2(float lo, float hi) {
    union { float f; u32 u; } a, b;
    a.f = lo; b.f = hi;
    return __builtin_amdgcn_perm(b.u + 0x8000u, a.u + 0x8000u, 0x07060302u);
}

#define LOG2E 1.44269504088896340736f

// ---------------------------------------------------------------------------
// K1 (merged): blocks [0,32) weight swizzle; [32,32+SB) segment bounds; rest
// node MLP -> hb (bf16 ONLY — R22's hb32 reverted: fp32 gather doubled the
// footprint past L2, FETCH 42->238 MB, mfma +36 µs).
// Panel(kt,nt): 16 n-rows x 32 u16, UNPADDED.
// SWZ: WB[0,4096) | V1B[4096,12288) | V2B[12288,16384)
// k-permutation (R16): X2/O1 features stored column-permuted in K4's XT
// (phys p holds logical feature sigma(p)=(p&3)*16+(p>>2)); matching B k-rows
// permuted here: V1 rows [64,128) and all V2 rows -> slot ((k&15)<<2)+(k>>4).
// ---------------------------------------------------------------------------
__global__ __launch_bounds__(256) void prep_mlp_kernel(
    const float* __restrict__ x, const float* __restrict__ u,
    const int* __restrict__ batch,
    const float* __restrict__ W1, const float* __restrict__ b1,
    const float* __restrict__ W2, const float* __restrict__ b2,
    const float* __restrict__ W3, const float* __restrict__ b3,
    u16* __restrict__ hb, int N,
    const float* __restrict__ Wg, const float* __restrict__ V1g,
    const float* __restrict__ V2g, u16* __restrict__ SWZ,
    const int* __restrict__ bh, int E, int G, int* __restrict__ seg_start,
    int SB)
{
    const int b = blockIdx.x, tid = threadIdx.x;
    if (b < 32) {                       // ---- weight swizzle ----
        int idx = b * 256 + tid;        // 0..8191
        int k = idx >> 6, n = idx & 63;
        // V1: permute k-rows >= 64 (Xhat half) to slot order sigma
        int s1 = (k < 64) ? k : (64 + (((k - 64) & 15) << 2) + ((k - 64) >> 4));
        int off1 = ((s1 >> 5) * 4 + (n >> 4)) * 512 + (n & 15) * 32 + ((s1 >> 3) & 3) * 8 + (s1 & 7);
        SWZ[4096 + off1] = f2b(V1g[idx]);
        if (idx < 4096) {
            int offw = ((k >> 5) * 4 + (n >> 4)) * 512 + (n & 15) * 32 + ((k >> 3) & 3) * 8 + (k & 7);
            SWZ[offw] = f2b(Wg[idx]);
            int s2 = ((k & 15) << 2) + (k >> 4);   // V2: permute ALL k-rows
            int off2 = ((s2 >> 5) * 4 + (n >> 4)) * 512 + (n & 15) * 32 + ((s2 >> 3) & 3) * 8 + (s2 & 7);
            SWZ[12288 + off2] = f2b(V2g[idx]);
        }
        return;
    }
    if (b < 32 + SB) {                  // ---- segment bounds ----
        int g = (b - 32) * 256 + tid;
        if (g > G) return;
        int lo = 0, hi = E;
        while (lo < hi) {
            int mid = (lo + hi) >> 1;
            if (bh[mid] < g) lo = mid + 1; else hi = mid;
        }
        seg_start[g] = lo;
        return;
    }
    // ---- node MLP ----
    __shared__ float inbuf[16][10];
    __shared__ float h1[16][64];
    __shared__ float h2[16][64];
    const int ni = tid >> 6, f = tid & 63;
    const int base = (b - 32 - SB) * 16;
    int nodes[4];
    #pragma unroll
    for (int s = 0; s < 4; ++s) {
        nodes[s] = min(base + s * 4 + ni, N - 1);
        if (f < 6)       inbuf[s * 4 + ni][f] = x[nodes[s] * 6 + f];
        else if (f < 10) inbuf[s * 4 + ni][f] = u[batch[nodes[s]] * 4 + (f - 6)];
    }
    __syncthreads();
    float acc[4];
    #pragma unroll
    for (int s = 0; s < 4; ++s) acc[s] = b1[f];
    #pragma unroll
    for (int k = 0; k < 10; ++k) {
        float w = W1[k * 64 + f];
        #pragma unroll
        for (int s = 0; s < 4; ++s) acc[s] = fmaf(inbuf[s * 4 + ni][k], w, acc[s]);
    }
    #pragma unroll
    for (int s = 0; s < 4; ++s) h1[s * 4 + ni][f] = fmaxf(acc[s], 0.f);
    __syncthreads();
    #pragma unroll
    for (int s = 0; s < 4; ++s) acc[s] = b2[f];
    #pragma unroll
    for (int k4 = 0; k4 < 16; ++k4) {
        float w0 = W2[(k4 * 4 + 0) * 64 + f];
        float w1 = W2[(k4 * 4 + 1) * 64 + f];
        float w2 = W2[(k4 * 4 + 2) * 64 + f];
        float w3 = W2[(k4 * 4 + 3) * 64 + f];
        #pragma unroll
        for (int s = 0; s < 4; ++s) {
            float4 hv = *(const float4*)&h1[s * 4 + ni][k4 * 4];
            acc[s] = fmaf(hv.x, w0, acc[s]);
            acc[s] = fmaf(hv.y, w1, acc[s]);
            acc[s] = fmaf(hv.z, w2, acc[s]);
            acc[s] = fmaf(hv.w, w3, acc[s]);
        }
    }
    #pragma unroll
    for (int s = 0; s < 4; ++s) h2[s * 4 + ni][f] = fmaxf(acc[s], 0.f);
    __syncthreads();
    #pragma unroll
    for (int s = 0; s < 4; ++s) acc[s] = b3[f];
    #pragma unroll
    for (int k4 = 0; k4 < 16; ++k4) {
        float w0 = W3[(k4 * 4 + 0) * 64 + f];
        float w1 = W3[(k4 * 4 + 1) * 64 + f];
        float w2 = W3[(k4 * 4 + 2) * 64 + f];
        float w3 = W3[(k4 * 4 + 3) * 64 + f];
        #pragma unroll
        for (int s = 0; s < 4; ++s) {
            float4 hv = *(const float4*)&h2[s * 4 + ni][k4 * 4];
            acc[s] = fmaf(hv.x, w0, acc[s]);
            acc[s] = fmaf(hv.y, w1, acc[s]);
            acc[s] = fmaf(hv.z, w2, acc[s]);
            acc[s] = fmaf(hv.w, w3, acc[s]);
        }
    }
    #pragma unroll
    for (int s = 0; s < 4; ++s) hb[nodes[s] * 64 + f] = f2b(acc[s]);
}

// ---------------------------------------------------------------------------
// K3 (R17-verified): softmax denominators + out[E..2E) ONLY. No Xh
// materialization — K4 re-gathers with identical op order.
// ---------------------------------------------------------------------------
__global__ __launch_bounds__(256) void gather_stats_kernel(
    const u16* __restrict__ hb, const int* __restrict__ hidx,
    const int* __restrict__ seg_start,
    float* __restrict__ Sinv, float* __restrict__ out, int E)
{
    __shared__ float ps[4][8][8];
    const int tid = threadIdx.x, lane = tid & 63, wid = tid >> 6;
    const int sub = lane >> 3, cl = lane & 7;
    const int g = blockIdx.x;
    const int e0 = seg_start[g], e1 = seg_start[g + 1];
    if (e1 <= e0) return;
    const int e1m1 = e1 - 1;
    const float gf = (float)g;

    for (int e = e0 + tid; e < e1; e += 256) out[E + e] = gf;

    float s[8] = {0.f, 0.f, 0.f, 0.f, 0.f, 0.f, 0.f, 0.f};
    for (int e = e0 + wid * 8 + sub; e < e1; e += 128) {
        #pragma unroll
        for (int j = 0; j < 4; ++j) {
            int ee = e + j * 32;
            int ec = min(ee, e1m1);
            int i0 = hidx[ec], i1 = hidx[E + ec], i2 = hidx[2 * E + ec];
            uint4 A0 = *(const uint4*)(hb + (size_t)i0 * 64 + cl * 8);
            uint4 A1 = *(const uint4*)(hb + (size_t)i1 * 64 + cl * 8);
            uint4 A2 = *(const uint4*)(hb + (size_t)i2 * 64 + cl * 8);
            u32 w0 = add3pack(A0.x, A1.x, A2.x);
            u32 w1 = add3pack(A0.y, A1.y, A2.y);
            u32 w2 = add3pack(A0.z, A1.z, A2.z);
            u32 w3 = add3pack(A0.w, A1.w, A2.w);
            if (ee < e1) {
                s[0] += __expf(blo(w0)); s[1] += __expf(bhi(w0));
                s[2] += __expf(blo(w1)); s[3] += __expf(bhi(w1));
                s[4] += __expf(blo(w2)); s[5] += __expf(bhi(w2));
                s[6] += __expf(blo(w3)); s[7] += __expf(bhi(w3));
            }
        }
    }
    #pragma unroll
    for (int k = 0; k < 8; ++k) {
        s[k] += __shfl_xor(s[k], 8);
        s[k] += __shfl_xor(s[k], 16);
        s[k] += __shfl_xor(s[k], 32);
    }
    if (lane < 8) {
        #pragma unroll
        for (int k = 0; k < 8; ++k) ps[wid][lane][k] = s[k];
    }
    __syncthreads();
    if (tid < 64) {
        int c8 = tid >> 3, cc = tid & 7;
        float S = ps[0][c8][cc] + ps[1][c8][cc] + ps[2][c8][cc] + ps[3][c8][cc];
        Sinv[g * 64 + tid] = 1.f / S;
    }
}

// ---------------------------------------------------------------------------
// K4: paired-tile MFMA chain. R23 delta: LDS DIET FOR OCCUPANCY.
// Only V1 (the hottest panel, 16 b128/iter) stays in LDS; W and V2 B-frags
// (8 reads/iter each, same 8 KB panel every iteration) are read DIRECTLY
// from global SWZ — L1/L2-resident. LDS 40960 -> 24576 B:
//   floor(160K/24576) = 6 blocks/CU (was 3) -> 24 waves/CU, 2x TLP to hide
//   the gather latency chain that R17-R22 showed is the 44%-stall cause.
// VGPR 72-84 under (256,3) allows 7 blocks; launch_bounds is a MIN (no cap).
// Numerics bit-identical to R19 (same weight values, same A-frag op order).
// Ledger: hb32 (R22, cache blowup), fusion x3 (R18/20/21), idx-prefetch
// (R19 null), (256,4) regalloc (R16 spill) — all reverted/avoided.
// ---------------------------------------------------------------------------
__global__ __launch_bounds__(256, 3) void mfma_seg_kernel(
    const u16* __restrict__ hb, const int* __restrict__ hidx,
    const int* __restrict__ seg_start,
    const u16* __restrict__ SWZ, const float* __restrict__ Sinv,
    const float* __restrict__ c1g, const float* __restrict__ c2g,
    const float* __restrict__ V3g, const float* __restrict__ c3g,
    float* __restrict__ out, int E)
{
    __shared__ u16 SW[8192];           // V1 panel only [was 16384 u16]
    __shared__ u16 XT_all[4][16 * 64]; // per-wave transpose tile, stride 64, swizzled

    const int tid = threadIdx.x, lane = tid & 63, wid = tid >> 6;
    const int nl = lane & 15, rq = lane >> 4;
    const int g = blockIdx.x;
    const int e0 = seg_start[g], e1 = seg_start[g + 1];
    const int L = e1 - e0;
    if (L <= 0) return;
    const int e1m1 = e1 - 1;

    {   // stage pre-swizzled V1: 16384 B = 1024 uint4
        const uint4* src = (const uint4*)(SWZ + 4096);
        uint4* dst = (uint4*)SW;
        for (int i = tid; i < 1024; i += 256) dst[i] = src[i];
    }
    __syncthreads();
    const u16* WB  = SWZ;              // global, L1/L2-hot (8 KB panel)
    const u16* V1B = SW;               // LDS
    const u16* V2B = SWZ + 12288;      // global, L1/L2-hot (8 KB panel)

    // identity B-frags for X C-layout redistribution (exact in bf16)
    bf16x8 I0, I1;
    #pragma unroll
    for (int j = 0; j < 8; ++j) {
        I0[j] = (rq * 8 + j == nl)      ? (short)0x3F80 : (short)0;
        I1[j] = (rq * 8 + j == nl + 16) ? (short)0x3F80 : (short)0;
    }

    float l2d[4], c1v[4], c2v[4], v3v[4];
    #pragma unroll
    for (int nt = 0; nt < 4; ++nt) {
        int col = nt * 16 + nl;
        l2d[nt] = __log2f(Sinv[g * 64 + col]);   // log2(dinv), hoisted
        c1v[nt] = c1g[col];
        c2v[nt] = c2g[col];
        v3v[nt] = V3g[col];
    }
    const float c3s = c3g[0];
    u16* XT = XT_all[wid];
    const f32x4 zf = {0.f, 0.f, 0.f, 0.f};

    // XT addressing: write base = row*64 + ((nl*4) ^ (rq<<4)) [row=rq*4+r]
    //                read  base = nl*64 + ((rq*8 [+32]) ^ ((nl>>2)<<4))
    const int xw_swz = rq << 4;
    const int xr_base = nl * 64;
    const int xr_swz  = (nl & 12) << 2;          // ((nl>>2)<<4)
    const int xr0 = xr_base + ((rq * 8) ^ xr_swz);
    const int xr1 = xr_base + ((rq * 8 + 32) ^ xr_swz);

    // gather + add3pack2 (identical op order to K3 => bit-identical)
    auto loadA = [&](int tt, bf16x8& A0, bf16x8& A1) {
        const int ec = min(e0 + tt * 16 + nl, e1m1);
        const int i0 = hidx[ec], i1 = hidx[E + ec], i2 = hidx[2 * E + ec];
        const u16* r0 = hb + (size_t)i0 * 64 + rq * 8;
        const u16* r1 = hb + (size_t)i1 * 64 + rq * 8;
        const u16* r2 = hb + (size_t)i2 * 64 + rq * 8;
        uint4 B0 = *(const uint4*)(r0), C0 = *(const uint4*)(r0 + 32);
        uint4 B1 = *(const uint4*)(r1), C1 = *(const uint4*)(r1 + 32);
        uint4 B2 = *(const uint4*)(r2), C2 = *(const uint4*)(r2 + 32);
        union { uint4 q; bf16x8 h; } u0, u1v;
        add3pack2(B0.x, B0.y, B1.x, B1.y, B2.x, B2.y, u0.q.x, u0.q.y);
        add3pack2(B0.z, B0.w, B1.z, B1.w, B2.z, B2.w, u0.q.z, u0.q.w);
        add3pack2(C0.x, C0.y, C1.x, C1.y, C2.x, C2.y, u1v.q.x, u1v.q.y);
        add3pack2(C0.z, C0.w, C1.z, C1.w, C2.z, C2.w, u1v.q.z, u1v.q.w);
        A0 = u0.h;
        A1 = u1v.h;
    };

    int t = wid;
    bf16x8 p0 = {}, p1 = {};
    if (t * 16 < L) loadA(t, p0, p1);

    for (; t * 16 < L; t += 8) {
        const int eB1 = e0 + t * 16;
        const int eB2 = eB1 + 64;                 // tile t+4 (may be phantom)

        bf16x8 a0 = p0, a1 = p1;                  // tile 1 (prefetched)
        bf16x8 a2, a3;
        loadA(t + 4, a2, a3);                     // tile 2 (clamped)
        if ((t + 8) * 16 < L) loadA(t + 8, p0, p1);  // prefetch next pair's 1st

        // xv in C-layout via identity MFMA, both tiles
        f32x4 xc1[4], xc2[4];
        xc1[0] = MFMA16(a0, I0, zf, 0, 0, 0);
        xc1[1] = MFMA16(a0, I1, zf, 0, 0, 0);
        xc1[2] = MFMA16(a1, I0, zf, 0, 0, 0);
        xc1[3] = MFMA16(a1, I1, zf, 0, 0, 0);
        xc2[0] = MFMA16(a2, I0, zf, 0, 0, 0);
        xc2[1] = MFMA16(a2, I1, zf, 0, 0, 0);
        xc2[2] = MFMA16(a3, I0, zf, 0, 0, 0);
        xc2[3] = MFMA16(a3, I1, zf, 0, 0, 0);

        // ---- layer W (B-frags from global SWZ, L1-hot) ----
        f32x4 acc1[4] = {zf, zf, zf, zf}, acc2t[4] = {zf, zf, zf, zf};
        #pragma unroll
        for (int nt = 0; nt < 4; ++nt) {
            bf16x8 b0 = *(const bf16x8*)(WB + (0 * 4 + nt) * 512 + nl * 32 + rq * 8);
            acc1[nt]  = MFMA16(a0, b0, acc1[nt], 0, 0, 0);
            acc2t[nt] = MFMA16(a2, b0, acc2t[nt], 0, 0, 0);
            bf16x8 b1 = *(const bf16x8*)(WB + (1 * 4 + nt) * 512 + nl * 32 + rq * 8);
            acc1[nt]  = MFMA16(a1, b1, acc1[nt], 0, 0, 0);
            acc2t[nt] = MFMA16(a3, b1, acc2t[nt], 0, 0, 0);
        }
        // Xhat epilogue: coef = exp2(xv*log2e + l2d); packed b64 store
        #pragma unroll
        for (int r = 0; r < 4; ++r) {
            float v0 = __builtin_amdgcn_exp2f(fmaf(xc1[0][r], LOG2E, l2d[0])) * fmaxf(acc1[0][r], 0.f);
            float v1 = __builtin_amdgcn_exp2f(fmaf(xc1[1][r], LOG2E, l2d[1])) * fmaxf(acc1[1][r], 0.f);
            float v2 = __builtin_amdgcn_exp2f(fmaf(xc1[2][r], LOG2E, l2d[2])) * fmaxf(acc1[2][r], 0.f);
            float v3 = __builtin_amdgcn_exp2f(fmaf(xc1[3][r], LOG2E, l2d[3])) * fmaxf(acc1[3][r], 0.f);
            uint2 w; w.x = pack2(v0, v1); w.y = pack2(v2, v3);
            *(uint2*)(XT + (rq * 4 + r) * 64 + ((nl * 4) ^ xw_swz)) = w;
        }
        bf16x8 x2a = *(const bf16x8*)(XT + xr0);
        bf16x8 x3a = *(const bf16x8*)(XT + xr1);
        #pragma unroll
        for (int r = 0; r < 4; ++r) {
            float v0 = __builtin_amdgcn_exp2f(fmaf(xc2[0][r], LOG2E, l2d[0])) * fmaxf(acc2t[0][r], 0.f);
            float v1 = __builtin_amdgcn_exp2f(fmaf(xc2[1][r], LOG2E, l2d[1])) * fmaxf(acc2t[1][r], 0.f);
            float v2 = __builtin_amdgcn_exp2f(fmaf(xc2[2][r], LOG2E, l2d[2])) * fmaxf(acc2t[2][r], 0.f);
            float v3 = __builtin_amdgcn_exp2f(fmaf(xc2[3][r], LOG2E, l2d[3])) * fmaxf(acc2t[3][r], 0.f);
            uint2 w; w.x = pack2(v0, v1); w.y = pack2(v2, v3);
            *(uint2*)(XT + (rq * 4 + r) * 64 + ((nl * 4) ^ xw_swz)) = w;
        }
        bf16x8 x2b = *(const bf16x8*)(XT + xr0);
        bf16x8 x3b = *(const bf16x8*)(XT + xr1);

        // ---- layer V1 (B-frags from LDS) ----
        f32x4 va[4], vb[4];
        #pragma unroll
        for (int nt = 0; nt < 4; ++nt) {
            va[nt][0] = c1v[nt]; va[nt][1] = c1v[nt];
            va[nt][2] = c1v[nt]; va[nt][3] = c1v[nt];
            vb[nt] = va[nt];
        }
        #pragma unroll
        for (int nt = 0; nt < 4; ++nt) {
            bf16x8 b0 = *(const bf16x8*)(V1B + (0 * 4 + nt) * 512 + nl * 32 + rq * 8);
            va[nt] = MFMA16(a0, b0, va[nt], 0, 0, 0);
            vb[nt] = MFMA16(a2, b0, vb[nt], 0, 0, 0);
            bf16x8 b1 = *(const bf16x8*)(V1B + (1 * 4 + nt) * 512 + nl * 32 + rq * 8);
            va[nt] = MFMA16(a1, b1, va[nt], 0, 0, 0);
            vb[nt] = MFMA16(a3, b1, vb[nt], 0, 0, 0);
        }
        #pragma unroll
        for (int nt = 0; nt < 4; ++nt) {
            bf16x8 b2 = *(const bf16x8*)(V1B + (2 * 4 + nt) * 512 + nl * 32 + rq * 8);
            va[nt] = MFMA16(x2a, b2, va[nt], 0, 0, 0);
            vb[nt] = MFMA16(x2b, b2, vb[nt], 0, 0, 0);
            bf16x8 b3 = *(const bf16x8*)(V1B + (3 * 4 + nt) * 512 + nl * 32 + rq * 8);
            va[nt] = MFMA16(x3a, b3, va[nt], 0, 0, 0);
            vb[nt] = MFMA16(x3b, b3, vb[nt], 0, 0, 0);
        }
        // O1 epilogue tile1 -> XT (packed), read o-frags; then tile2
        #pragma unroll
        for (int r = 0; r < 4; ++r) {
            uint2 w;
            w.x = pack2(fmaxf(va[0][r], 0.f), fmaxf(va[1][r], 0.f));
            w.y = pack2(fmaxf(va[2][r], 0.f), fmaxf(va[3][r], 0.f));
            *(uint2*)(XT + (rq * 4 + r) * 64 + ((nl * 4) ^ xw_swz)) = w;
        }
        bf16x8 o0a = *(const bf16x8*)(XT + xr0);
        bf16x8 o1a = *(const bf16x8*)(XT + xr1);
        #pragma unroll
        for (int r = 0; r < 4; ++r) {
            uint2 w;
            w.x = pack2(fmaxf(vb[0][r], 0.f), fmaxf(vb[1][r], 0.f));
            w.y = pack2(fmaxf(vb[2][r], 0.f), fmaxf(vb[3][r], 0.f));
            *(uint2*)(XT + (rq * 4 + r) * 64 + ((nl * 4) ^ xw_swz)) = w;
        }
        bf16x8 o0b = *(const bf16x8*)(XT + xr0);
        bf16x8 o1b = *(const bf16x8*)(XT + xr1);

        // ---- layer V2 (B-frags from global SWZ, L1-hot) ----
        f32x4 wa[4], wb2[4];
        #pragma unroll
        for (int nt = 0; nt < 4; ++nt) {
            wa[nt][0] = c2v[nt]; wa[nt][1] = c2v[nt];
            wa[nt][2] = c2v[nt]; wa[nt][3] = c2v[nt];
            wb2[nt] = wa[nt];
        }
        #pragma unroll
        for (int nt = 0; nt < 4; ++nt) {
            bf16x8 b0 = *(const bf16x8*)(V2B + (0 * 4 + nt) * 512 + nl * 32 + rq * 8);
            wa[nt]  = MFMA16(o0a, b0, wa[nt], 0, 0, 0);
            wb2[nt] = MFMA16(o0b, b0, wb2[nt], 0, 0, 0);
            bf16x8 b1 = *(const bf16x8*)(V2B + (1 * 4 + nt) * 512 + nl * 32 + rq * 8);
            wa[nt]  = MFMA16(o1a, b1, wa[nt], 0, 0, 0);
            wb2[nt] = MFMA16(o1b, b1, wb2[nt], 0, 0, 0);
        }

        // ---- V3 + sigmoid, both tiles ----
        float sra[4], srb[4];
        #pragma unroll
        for (int r = 0; r < 4; ++r) {
            float u1 = 0.f, u2 = 0.f;
            #pragma unroll
            for (int nt = 0; nt < 4; ++nt) {
                u1 = fmaf(fmaxf(wa[nt][r],  0.f), v3v[nt], u1);
                u2 = fmaf(fmaxf(wb2[nt][r], 0.f), v3v[nt], u2);
            }
            u1 += __shfl_xor(u1, 1); u2 += __shfl_xor(u2, 1);
            u1 += __shfl_xor(u1, 2); u2 += __shfl_xor(u2, 2);
            u1 += __shfl_xor(u1, 4); u2 += __shfl_xor(u2, 4);
            u1 += __shfl_xor(u1, 8); u2 += __shfl_xor(u2, 8);
            sra[r] = 1.f / (1.f + __expf(-(u1 + c3s)));
            srb[r] = 1.f / (1.f + __expf(-(u2 + c3s)));
        }
        if (nl == 0) {
            const int ra = eB1 + rq * 4;
            if (ra + 3 < e1) {                    // packed float4 store
                *(float4*)(out + ra) = make_float4(sra[0], sra[1], sra[2], sra[3]);
            } else {
                #pragma unroll
                for (int r = 0; r < 4; ++r)
                    if (ra + r < e1) out[ra + r] = sra[r];
            }
            const int rb = eB2 + rq * 4;
            if (rb + 3 < e1) {
                *(float4*)(out + rb) = make_float4(srb[0], srb[1], srb[2], srb[3]);
            } else {
                #pragma unroll
                for (int r = 0; r < 4; ++r)
                    if (rb + r < e1) out[rb + r] = srb[r];
            }
        }
    }
}

// ---------------------------------------------------------------------------
extern "C" void kernel_launch(void* const* d_in, const int* in_sizes, int n_in,
                              void* d_out, int out_size, void* d_ws, size_t ws_size,
                              hipStream_t stream) {
    const float* x     = (const float*)d_in[0];
    const float* u     = (const float*)d_in[1];
    const int*   batch = (const int*)  d_in[2];
    const int*   hidx  = (const int*)  d_in[3];
    const int*   bh    = (const int*)  d_in[4];
    const float* W1 = (const float*)d_in[6];
    const float* b1 = (const float*)d_in[7];
    const float* W2 = (const float*)d_in[8];
    const float* b2 = (const float*)d_in[9];
    const float* W3 = (const float*)d_in[10];
    const float* b3 = (const float*)d_in[11];
    const float* Wg = (const float*)d_in[12];
    const float* V1 = (const float*)d_in[13];
    const float* c1 = (const float*)d_in[14];
    const float* V2 = (const float*)d_in[15];
    const float* c2 = (const float*)d_in[16];
    const float* V3 = (const float*)d_in[17];
    const float* c3 = (const float*)d_in[18];

    const int N = in_sizes[0] / 6;
    const int G = in_sizes[1] / 4;
    const int E = in_sizes[4];

    // ws layout (R23: hb32 removed)
    char* ws = (char*)d_ws;
    size_t off = 0;
    u16* hb = (u16*)(ws + off);            off += (size_t)N * 64 * 2;
    int* seg_start = (int*)(ws + off);     off += ((size_t)G + 1) * 4;
    off = (off + 255) & ~(size_t)255;
    u16* SWZ = (u16*)(ws + off);           off += 16384 * 2;
    float* Sinv = (float*)(ws + off);      off += (size_t)G * 64 * 4;
    float* out = (float*)d_out;

    const int SB = (G + 256) / 256;
    const int NB = (N + 15) / 16;
    prep_mlp_kernel<<<32 + SB + NB, 256, 0, stream>>>(
        x, u, batch, W1, b1, W2, b2, W3, b3, hb, N,
        Wg, V1, V2, SWZ, bh, E, G, seg_start, SB);
    gather_stats_kernel<<<G, 256, 0, stream>>>(hb, hidx, seg_start, Sinv, out, E);
    mfma_seg_kernel<<<G, 256, 0, stream>>>(
        hb, hidx, seg_start, SWZ, Sinv, c1, c2, V3, c3, out, E);
}

// Round 9
// 237.594 us; speedup vs baseline: 1.1993x; 1.1993x over previous
//
#include <hip/hip_runtime.h>
#include <math.h>

typedef short bf16x8 __attribute__((ext_vector_type(8)));
typedef float f32x4  __attribute__((ext_vector_type(4)));
typedef unsigned short u16;
typedef unsigned int   u32;

#define MFMA16 __builtin_amdgcn_mfma_f32_16x16x32_bf16

__device__ __forceinline__ u16 f2b(float x) {   // fp32 -> bf16 RNE
    union { float f; unsigned u; } v; v.f = x;
    unsigned r = v.u + 0x7fffu + ((v.u >> 16) & 1u);
    return (u16)(r >> 16);
}
// round-half-up bf16 (2 VALU vs 4; <=0.5ulp) — Xhat/O1 quantization
__device__ __forceinline__ u16 f2bu(float x) {
    union { float f; unsigned u; } v; v.f = x;
    return (u16)((v.u + 0x8000u) >> 16);
}
__device__ __forceinline__ float b2f(u16 h) {
    union { unsigned u; float f; } v; v.u = ((unsigned)h) << 16;
    return v.f;
}
__device__ __forceinline__ float blo(u32 w) {
    union { u32 u; float f; } v; v.u = w << 16; return v.f;
}
__device__ __forceinline__ float bhi(u32 w) {
    union { u32 u; float f; } v; v.u = w & 0xffff0000u; return v.f;
}
// sum 3 packed bf16 pairs in fp32 (order i0+i1+i2), repack bf16 HALF-UP via
// one v_perm_b32 (R14-verified). K3's exp and K4's recomputed A-frags use the
// IDENTICAL per-element op order -> bit-identical values.
__device__ __forceinline__ u32 add3pack(u32 x, u32 y, u32 z) {
    union { float f; u32 u; } lo, hi;
    lo.f = blo(x) + blo(y) + blo(z);
    hi.f = bhi(x) + bhi(y) + bhi(z);
    return __builtin_amdgcn_perm(hi.u + 0x8000u, lo.u + 0x8000u, 0x07060302u);
}
// pack 2 fp32 -> 2 bf16 half-up in one u32 (low u16 = f2bu(lo), hi = f2bu(hi))
__device__ __forceinline__ u32 pack2(float lo, float hi) {
    union { float f; u32 u; } a, b;
    a.f = lo; b.f = hi;
    return __builtin_amdgcn_perm(b.u + 0x8000u, a.u + 0x8000u, 0x07060302u);
}

#define LOG2E 1.44269504088896340736f

// ---------------------------------------------------------------------------
// K1 (merged): blocks [0,32) weight swizzle; [32,32+SB) segment bounds; rest
// node MLP -> hb (bf16). h bit-identical to R10.
// Panel(kt,nt): 16 n-rows x 32 u16, UNPADDED.
// SWZ: WB[0,4096) | V1B[4096,12288) | V2B[12288,16384)
// k-permutation (R16): X2/O1 features stored column-permuted in K4's XT
// (phys p holds logical feature sigma(p)=(p&3)*16+(p>>2)); matching B k-rows
// permuted here: V1 rows [64,128) and all V2 rows -> slot ((k&15)<<2)+(k>>4).
// ---------------------------------------------------------------------------
__global__ __launch_bounds__(256) void prep_mlp_kernel(
    const float* __restrict__ x, const float* __restrict__ u,
    const int* __restrict__ batch,
    const float* __restrict__ W1, const float* __restrict__ b1,
    const float* __restrict__ W2, const float* __restrict__ b2,
    const float* __restrict__ W3, const float* __restrict__ b3,
    u16* __restrict__ hb, int N,
    const float* __restrict__ Wg, const float* __restrict__ V1g,
    const float* __restrict__ V2g, u16* __restrict__ SWZ,
    const int* __restrict__ bh, int E, int G, int* __restrict__ seg_start,
    int SB)
{
    const int b = blockIdx.x, tid = threadIdx.x;
    if (b < 32) {                       // ---- weight swizzle ----
        int idx = b * 256 + tid;        // 0..8191
        int k = idx >> 6, n = idx & 63;
        // V1: permute k-rows >= 64 (Xhat half) to slot order sigma
        int s1 = (k < 64) ? k : (64 + (((k - 64) & 15) << 2) + ((k - 64) >> 4));
        int off1 = ((s1 >> 5) * 4 + (n >> 4)) * 512 + (n & 15) * 32 + ((s1 >> 3) & 3) * 8 + (s1 & 7);
        SWZ[4096 + off1] = f2b(V1g[idx]);
        if (idx < 4096) {
            int offw = ((k >> 5) * 4 + (n >> 4)) * 512 + (n & 15) * 32 + ((k >> 3) & 3) * 8 + (k & 7);
            SWZ[offw] = f2b(Wg[idx]);
            int s2 = ((k & 15) << 2) + (k >> 4);   // V2: permute ALL k-rows
            int off2 = ((s2 >> 5) * 4 + (n >> 4)) * 512 + (n & 15) * 32 + ((s2 >> 3) & 3) * 8 + (s2 & 7);
            SWZ[12288 + off2] = f2b(V2g[idx]);
        }
        return;
    }
    if (b < 32 + SB) {                  // ---- segment bounds ----
        int g = (b - 32) * 256 + tid;
        if (g > G) return;
        int lo = 0, hi = E;
        while (lo < hi) {
            int mid = (lo + hi) >> 1;
            if (bh[mid] < g) lo = mid + 1; else hi = mid;
        }
        seg_start[g] = lo;
        return;
    }
    // ---- node MLP ----
    __shared__ float inbuf[16][10];
    __shared__ float h1[16][64];
    __shared__ float h2[16][64];
    const int ni = tid >> 6, f = tid & 63;
    const int base = (b - 32 - SB) * 16;
    int nodes[4];
    #pragma unroll
    for (int s = 0; s < 4; ++s) {
        nodes[s] = min(base + s * 4 + ni, N - 1);
        if (f < 6)       inbuf[s * 4 + ni][f] = x[nodes[s] * 6 + f];
        else if (f < 10) inbuf[s * 4 + ni][f] = u[batch[nodes[s]] * 4 + (f - 6)];
    }
    __syncthreads();
    float acc[4];
    #pragma unroll
    for (int s = 0; s < 4; ++s) acc[s] = b1[f];
    #pragma unroll
    for (int k = 0; k < 10; ++k) {
        float w = W1[k * 64 + f];
        #pragma unroll
        for (int s = 0; s < 4; ++s) acc[s] = fmaf(inbuf[s * 4 + ni][k], w, acc[s]);
    }
    #pragma unroll
    for (int s = 0; s < 4; ++s) h1[s * 4 + ni][f] = fmaxf(acc[s], 0.f);
    __syncthreads();
    #pragma unroll
    for (int s = 0; s < 4; ++s) acc[s] = b2[f];
    #pragma unroll
    for (int k4 = 0; k4 < 16; ++k4) {
        float w0 = W2[(k4 * 4 + 0) * 64 + f];
        float w1 = W2[(k4 * 4 + 1) * 64 + f];
        float w2 = W2[(k4 * 4 + 2) * 64 + f];
        float w3 = W2[(k4 * 4 + 3) * 64 + f];
        #pragma unroll
        for (int s = 0; s < 4; ++s) {
            float4 hv = *(const float4*)&h1[s * 4 + ni][k4 * 4];
            acc[s] = fmaf(hv.x, w0, acc[s]);
            acc[s] = fmaf(hv.y, w1, acc[s]);
            acc[s] = fmaf(hv.z, w2, acc[s]);
            acc[s] = fmaf(hv.w, w3, acc[s]);
        }
    }
    #pragma unroll
    for (int s = 0; s < 4; ++s) h2[s * 4 + ni][f] = fmaxf(acc[s], 0.f);
    __syncthreads();
    #pragma unroll
    for (int s = 0; s < 4; ++s) acc[s] = b3[f];
    #pragma unroll
    for (int k4 = 0; k4 < 16; ++k4) {
        float w0 = W3[(k4 * 4 + 0) * 64 + f];
        float w1 = W3[(k4 * 4 + 1) * 64 + f];
        float w2 = W3[(k4 * 4 + 2) * 64 + f];
        float w3 = W3[(k4 * 4 + 3) * 64 + f];
        #pragma unroll
        for (int s = 0; s < 4; ++s) {
            float4 hv = *(const float4*)&h2[s * 4 + ni][k4 * 4];
            acc[s] = fmaf(hv.x, w0, acc[s]);
            acc[s] = fmaf(hv.y, w1, acc[s]);
            acc[s] = fmaf(hv.z, w2, acc[s]);
            acc[s] = fmaf(hv.w, w3, acc[s]);
        }
    }
    #pragma unroll
    for (int s = 0; s < 4; ++s) hb[nodes[s] * 64 + f] = f2b(acc[s]);
}

// ---------------------------------------------------------------------------
// K3 (R17-verified): softmax denominators + out[E..2E) ONLY. No Xh
// materialization — K4 re-gathers from hb (4 MB, L2/L3-resident) and
// recomputes add3pack in the identical order, so values stay bit-identical.
// ---------------------------------------------------------------------------
__global__ __launch_bounds__(256) void gather_stats_kernel(
    const u16* __restrict__ hb, const int* __restrict__ hidx,
    const int* __restrict__ seg_start,
    float* __restrict__ Sinv, float* __restrict__ out, int E)
{
    __shared__ float ps[4][8][8];
    const int tid = threadIdx.x, lane = tid & 63, wid = tid >> 6;
    const int sub = lane >> 3, cl = lane & 7;
    const int g = blockIdx.x;
    const int e0 = seg_start[g], e1 = seg_start[g + 1];
    if (e1 <= e0) return;
    const int e1m1 = e1 - 1;
    const float gf = (float)g;

    for (int e = e0 + tid; e < e1; e += 256) out[E + e] = gf;

    float s[8] = {0.f, 0.f, 0.f, 0.f, 0.f, 0.f, 0.f, 0.f};
    for (int e = e0 + wid * 8 + sub; e < e1; e += 128) {
        #pragma unroll
        for (int j = 0; j < 4; ++j) {
            int ee = e + j * 32;
            int ec = min(ee, e1m1);
            int i0 = hidx[ec], i1 = hidx[E + ec], i2 = hidx[2 * E + ec];
            uint4 A0 = *(const uint4*)(hb + (size_t)i0 * 64 + cl * 8);
            uint4 A1 = *(const uint4*)(hb + (size_t)i1 * 64 + cl * 8);
            uint4 A2 = *(const uint4*)(hb + (size_t)i2 * 64 + cl * 8);
            u32 w0 = add3pack(A0.x, A1.x, A2.x);
            u32 w1 = add3pack(A0.y, A1.y, A2.y);
            u32 w2 = add3pack(A0.z, A1.z, A2.z);
            u32 w3 = add3pack(A0.w, A1.w, A2.w);
            if (ee < e1) {
                s[0] += __expf(blo(w0)); s[1] += __expf(bhi(w0));
                s[2] += __expf(blo(w1)); s[3] += __expf(bhi(w1));
                s[4] += __expf(blo(w2)); s[5] += __expf(bhi(w2));
                s[6] += __expf(blo(w3)); s[7] += __expf(bhi(w3));
            }
        }
    }
    #pragma unroll
    for (int k = 0; k < 8; ++k) {
        s[k] += __shfl_xor(s[k], 8);
        s[k] += __shfl_xor(s[k], 16);
        s[k] += __shfl_xor(s[k], 32);
    }
    if (lane < 8) {
        #pragma unroll
        for (int k = 0; k < 8; ++k) ps[wid][lane][k] = s[k];
    }
    __syncthreads();
    if (tid < 64) {
        int c8 = tid >> 3, cc = tid & 7;
        float S = ps[0][c8][cc] + ps[1][c8][cc] + ps[2][c8][cc] + ps[3][c8][cc];
        Sinv[g * 64 + tid] = 1.f / S;
    }
}

// ---------------------------------------------------------------------------
// K4: paired-tile MFMA chain = EXACT R17 champion (238.2 µs total) + R24's
// single delta: s_setprio(1/0) around the three MFMA clusters (T5). The
// loop has NO cross-wave barriers — waves progress at independent phases,
// which is the regime where setprio measured +4-7% (attn, m191); it nulls
// only in barrier-lockstep loops (m190). Risk ~0, bit-identical numerics.
// Ledger of measured-and-reverted: hb32 (R22 cache blowup), LDS-diet (R23
// latency), fusion x3 (R18/20/21), idx-prefetch+pk_add (R19 null),
// (256,4) (R16 spill).
// LDS: 32768(SW) + 8192(XT) = 40960 B; 3 blocks/CU.
// ---------------------------------------------------------------------------
__global__ __launch_bounds__(256, 3) void mfma_seg_kernel(
    const u16* __restrict__ hb, const int* __restrict__ hidx,
    const int* __restrict__ seg_start,
    const u16* __restrict__ SWZ, const float* __restrict__ Sinv,
    const float* __restrict__ c1g, const float* __restrict__ c2g,
    const float* __restrict__ V3g, const float* __restrict__ c3g,
    float* __restrict__ out, int E)
{
    __shared__ u16 SW[16384];          // WB[0,4096)+V1B[4096,12288)+V2B[12288,16384)
    __shared__ u16 XT_all[4][16 * 64]; // per-wave transpose tile, stride 64, swizzled

    const int tid = threadIdx.x, lane = tid & 63, wid = tid >> 6;
    const int nl = lane & 15, rq = lane >> 4;
    const int g = blockIdx.x;
    const int e0 = seg_start[g], e1 = seg_start[g + 1];
    const int L = e1 - e0;
    if (L <= 0) return;
    const int e1m1 = e1 - 1;

    {   // stage pre-swizzled W+V1+V2: 32768 B = 2048 uint4
        const uint4* src = (const uint4*)SWZ;
        uint4* dst = (uint4*)SW;
        for (int i = tid; i < 2048; i += 256) dst[i] = src[i];
    }
    __syncthreads();
    const u16* WB  = SW;
    const u16* V1B = SW + 4096;
    const u16* V2B = SW + 12288;

    // identity B-frags for X C-layout redistribution (exact in bf16)
    bf16x8 I0, I1;
    #pragma unroll
    for (int j = 0; j < 8; ++j) {
        I0[j] = (rq * 8 + j == nl)      ? (short)0x3F80 : (short)0;
        I1[j] = (rq * 8 + j == nl + 16) ? (short)0x3F80 : (short)0;
    }

    float l2d[4], c1v[4], c2v[4], v3v[4];
    #pragma unroll
    for (int nt = 0; nt < 4; ++nt) {
        int col = nt * 16 + nl;
        l2d[nt] = __log2f(Sinv[g * 64 + col]);   // log2(dinv), hoisted
        c1v[nt] = c1g[col];
        c2v[nt] = c2g[col];
        v3v[nt] = V3g[col];
    }
    const float c3s = c3g[0];
    u16* XT = XT_all[wid];
    const f32x4 zf = {0.f, 0.f, 0.f, 0.f};

    // XT addressing: write base = row*64 + ((nl*4) ^ (rq<<4)) [row=rq*4+r]
    //                read  base = nl*64 + ((rq*8 [+32]) ^ ((nl>>2)<<4))
    const int xw_swz = rq << 4;
    const int xr_base = nl * 64;
    const int xr_swz  = (nl & 12) << 2;          // ((nl>>2)<<4)
    const int xr0 = xr_base + ((rq * 8) ^ xr_swz);
    const int xr1 = xr_base + ((rq * 8 + 32) ^ xr_swz);

    // gather + add3pack (identical op order to K3 => bit-identical)
    auto loadA = [&](int tt, bf16x8& A0, bf16x8& A1) {
        const int ec = min(e0 + tt * 16 + nl, e1m1);
        const int i0 = hidx[ec], i1 = hidx[E + ec], i2 = hidx[2 * E + ec];
        const u16* r0 = hb + (size_t)i0 * 64 + rq * 8;
        const u16* r1 = hb + (size_t)i1 * 64 + rq * 8;
        const u16* r2 = hb + (size_t)i2 * 64 + rq * 8;
        uint4 B0 = *(const uint4*)(r0), C0 = *(const uint4*)(r0 + 32);
        uint4 B1 = *(const uint4*)(r1), C1 = *(const uint4*)(r1 + 32);
        uint4 B2 = *(const uint4*)(r2), C2 = *(const uint4*)(r2 + 32);
        union { uint4 q; bf16x8 h; } u0, u1v;
        u0.q.x  = add3pack(B0.x, B1.x, B2.x);
        u0.q.y  = add3pack(B0.y, B1.y, B2.y);
        u0.q.z  = add3pack(B0.z, B1.z, B2.z);
        u0.q.w  = add3pack(B0.w, B1.w, B2.w);
        u1v.q.x = add3pack(C0.x, C1.x, C2.x);
        u1v.q.y = add3pack(C0.y, C1.y, C2.y);
        u1v.q.z = add3pack(C0.z, C1.z, C2.z);
        u1v.q.w = add3pack(C0.w, C1.w, C2.w);
        A0 = u0.h;
        A1 = u1v.h;
    };

    int t = wid;
    bf16x8 p0 = {}, p1 = {};
    if (t * 16 < L) loadA(t, p0, p1);

    for (; t * 16 < L; t += 8) {
        const int eB1 = e0 + t * 16;
        const int eB2 = eB1 + 64;                 // tile t+4 (may be phantom)

        bf16x8 a0 = p0, a1 = p1;                  // tile 1 (prefetched)
        bf16x8 a2, a3;
        loadA(t + 4, a2, a3);                     // tile 2 (clamped)
        if ((t + 8) * 16 < L) loadA(t + 8, p0, p1);  // prefetch next pair's 1st

        // ---- MFMA cluster 1: xc identity + layer W (setprio, T5) ----
        __builtin_amdgcn_s_setprio(1);
        f32x4 xc1[4], xc2[4];
        xc1[0] = MFMA16(a0, I0, zf, 0, 0, 0);
        xc1[1] = MFMA16(a0, I1, zf, 0, 0, 0);
        xc1[2] = MFMA16(a1, I0, zf, 0, 0, 0);
        xc1[3] = MFMA16(a1, I1, zf, 0, 0, 0);
        xc2[0] = MFMA16(a2, I0, zf, 0, 0, 0);
        xc2[1] = MFMA16(a2, I1, zf, 0, 0, 0);
        xc2[2] = MFMA16(a3, I0, zf, 0, 0, 0);
        xc2[3] = MFMA16(a3, I1, zf, 0, 0, 0);

        f32x4 acc1[4] = {zf, zf, zf, zf}, acc2t[4] = {zf, zf, zf, zf};
        #pragma unroll
        for (int nt = 0; nt < 4; ++nt) {
            bf16x8 b0 = *(const bf16x8*)(WB + (0 * 4 + nt) * 512 + nl * 32 + rq * 8);
            acc1[nt]  = MFMA16(a0, b0, acc1[nt], 0, 0, 0);
            acc2t[nt] = MFMA16(a2, b0, acc2t[nt], 0, 0, 0);
            bf16x8 b1 = *(const bf16x8*)(WB + (1 * 4 + nt) * 512 + nl * 32 + rq * 8);
            acc1[nt]  = MFMA16(a1, b1, acc1[nt], 0, 0, 0);
            acc2t[nt] = MFMA16(a3, b1, acc2t[nt], 0, 0, 0);
        }
        __builtin_amdgcn_s_setprio(0);

        // Xhat epilogue: coef = exp2(xv*log2e + l2d); packed b64 store
        #pragma unroll
        for (int r = 0; r < 4; ++r) {
            float v0 = __builtin_amdgcn_exp2f(fmaf(xc1[0][r], LOG2E, l2d[0])) * fmaxf(acc1[0][r], 0.f);
            float v1 = __builtin_amdgcn_exp2f(fmaf(xc1[1][r], LOG2E, l2d[1])) * fmaxf(acc1[1][r], 0.f);
            float v2 = __builtin_amdgcn_exp2f(fmaf(xc1[2][r], LOG2E, l2d[2])) * fmaxf(acc1[2][r], 0.f);
            float v3 = __builtin_amdgcn_exp2f(fmaf(xc1[3][r], LOG2E, l2d[3])) * fmaxf(acc1[3][r], 0.f);
            uint2 w; w.x = pack2(v0, v1); w.y = pack2(v2, v3);
            *(uint2*)(XT + (rq * 4 + r) * 64 + ((nl * 4) ^ xw_swz)) = w;
        }
        bf16x8 x2a = *(const bf16x8*)(XT + xr0);
        bf16x8 x3a = *(const bf16x8*)(XT + xr1);
        #pragma unroll
        for (int r = 0; r < 4; ++r) {
            float v0 = __builtin_amdgcn_exp2f(fmaf(xc2[0][r], LOG2E, l2d[0])) * fmaxf(acc2t[0][r], 0.f);
            float v1 = __builtin_amdgcn_exp2f(fmaf(xc2[1][r], LOG2E, l2d[1])) * fmaxf(acc2t[1][r], 0.f);
            float v2 = __builtin_amdgcn_exp2f(fmaf(xc2[2][r], LOG2E, l2d[2])) * fmaxf(acc2t[2][r], 0.f);
            float v3 = __builtin_amdgcn_exp2f(fmaf(xc2[3][r], LOG2E, l2d[3])) * fmaxf(acc2t[3][r], 0.f);
            uint2 w; w.x = pack2(v0, v1); w.y = pack2(v2, v3);
            *(uint2*)(XT + (rq * 4 + r) * 64 + ((nl * 4) ^ xw_swz)) = w;
        }
        bf16x8 x2b = *(const bf16x8*)(XT + xr0);
        bf16x8 x3b = *(const bf16x8*)(XT + xr1);

        // ---- MFMA cluster 2: layer V1 (setprio, T5) ----
        f32x4 va[4], vb[4];
        #pragma unroll
        for (int nt = 0; nt < 4; ++nt) {
            va[nt][0] = c1v[nt]; va[nt][1] = c1v[nt];
            va[nt][2] = c1v[nt]; va[nt][3] = c1v[nt];
            vb[nt] = va[nt];
        }
        __builtin_amdgcn_s_setprio(1);
        #pragma unroll
        for (int nt = 0; nt < 4; ++nt) {
            bf16x8 b0 = *(const bf16x8*)(V1B + (0 * 4 + nt) * 512 + nl * 32 + rq * 8);
            va[nt] = MFMA16(a0, b0, va[nt], 0, 0, 0);
            vb[nt] = MFMA16(a2, b0, vb[nt], 0, 0, 0);
            bf16x8 b1 = *(const bf16x8*)(V1B + (1 * 4 + nt) * 512 + nl * 32 + rq * 8);
            va[nt] = MFMA16(a1, b1, va[nt], 0, 0, 0);
            vb[nt] = MFMA16(a3, b1, vb[nt], 0, 0, 0);
        }
        #pragma unroll
        for (int nt = 0; nt < 4; ++nt) {
            bf16x8 b2 = *(const bf16x8*)(V1B + (2 * 4 + nt) * 512 + nl * 32 + rq * 8);
            va[nt] = MFMA16(x2a, b2, va[nt], 0, 0, 0);
            vb[nt] = MFMA16(x2b, b2, vb[nt], 0, 0, 0);
            bf16x8 b3 = *(const bf16x8*)(V1B + (3 * 4 + nt) * 512 + nl * 32 + rq * 8);
            va[nt] = MFMA16(x3a, b3, va[nt], 0, 0, 0);
            vb[nt] = MFMA16(x3b, b3, vb[nt], 0, 0, 0);
        }
        __builtin_amdgcn_s_setprio(0);

        // O1 epilogue tile1 -> XT (packed), read o-frags; then tile2
        #pragma unroll
        for (int r = 0; r < 4; ++r) {
            uint2 w;
            w.x = pack2(fmaxf(va[0][r], 0.f), fmaxf(va[1][r], 0.f));
            w.y = pack2(fmaxf(va[2][r], 0.f), fmaxf(va[3][r], 0.f));
            *(uint2*)(XT + (rq * 4 + r) * 64 + ((nl * 4) ^ xw_swz)) = w;
        }
        bf16x8 o0a = *(const bf16x8*)(XT + xr0);
        bf16x8 o1a = *(const bf16x8*)(XT + xr1);
        #pragma unroll
        for (int r = 0; r < 4; ++r) {
            uint2 w;
            w.x = pack2(fmaxf(vb[0][r], 0.f), fmaxf(vb[1][r], 0.f));
            w.y = pack2(fmaxf(vb[2][r], 0.f), fmaxf(vb[3][r], 0.f));
            *(uint2*)(XT + (rq * 4 + r) * 64 + ((nl * 4) ^ xw_swz)) = w;
        }
        bf16x8 o0b = *(const bf16x8*)(XT + xr0);
        bf16x8 o1b = *(const bf16x8*)(XT + xr1);

        // ---- MFMA cluster 3: layer V2 (setprio, T5) ----
        f32x4 wa[4], wb2[4];
        #pragma unroll
        for (int nt = 0; nt < 4; ++nt) {
            wa[nt][0] = c2v[nt]; wa[nt][1] = c2v[nt];
            wa[nt][2] = c2v[nt]; wa[nt][3] = c2v[nt];
            wb2[nt] = wa[nt];
        }
        __builtin_amdgcn_s_setprio(1);
        #pragma unroll
        for (int nt = 0; nt < 4; ++nt) {
            bf16x8 b0 = *(const bf16x8*)(V2B + (0 * 4 + nt) * 512 + nl * 32 + rq * 8);
            wa[nt]  = MFMA16(o0a, b0, wa[nt], 0, 0, 0);
            wb2[nt] = MFMA16(o0b, b0, wb2[nt], 0, 0, 0);
            bf16x8 b1 = *(const bf16x8*)(V2B + (1 * 4 + nt) * 512 + nl * 32 + rq * 8);
            wa[nt]  = MFMA16(o1a, b1, wa[nt], 0, 0, 0);
            wb2[nt] = MFMA16(o1b, b1, wb2[nt], 0, 0, 0);
        }
        __builtin_amdgcn_s_setprio(0);

        // ---- V3 + sigmoid, both tiles ----
        float sra[4], srb[4];
        #pragma unroll
        for (int r = 0; r < 4; ++r) {
            float u1 = 0.f, u2 = 0.f;
            #pragma unroll
            for (int nt = 0; nt < 4; ++nt) {
                u1 = fmaf(fmaxf(wa[nt][r],  0.f), v3v[nt], u1);
                u2 = fmaf(fmaxf(wb2[nt][r], 0.f), v3v[nt], u2);
            }
            u1 += __shfl_xor(u1, 1); u2 += __shfl_xor(u2, 1);
            u1 += __shfl_xor(u1, 2); u2 += __shfl_xor(u2, 2);
            u1 += __shfl_xor(u1, 4); u2 += __shfl_xor(u2, 4);
            u1 += __shfl_xor(u1, 8); u2 += __shfl_xor(u2, 8);
            sra[r] = 1.f / (1.f + __expf(-(u1 + c3s)));
            srb[r] = 1.f / (1.f + __expf(-(u2 + c3s)));
        }
        if (nl == 0) {
            const int ra = eB1 + rq * 4;
            if (ra + 3 < e1) {                    // packed float4 store
                *(float4*)(out + ra) = make_float4(sra[0], sra[1], sra[2], sra[3]);
            } else {
                #pragma unroll
                for (int r = 0; r < 4; ++r)
                    if (ra + r < e1) out[ra + r] = sra[r];
            }
            const int rb = eB2 + rq * 4;
            if (rb + 3 < e1) {
                *(float4*)(out + rb) = make_float4(srb[0], srb[1], srb[2], srb[3]);
            } else {
                #pragma unroll
                for (int r = 0; r < 4; ++r)
                    if (rb + r < e1) out[rb + r] = srb[r];
            }
        }
    }
}

// ---------------------------------------------------------------------------
extern "C" void kernel_launch(void* const* d_in, const int* in_sizes, int n_in,
                              void* d_out, int out_size, void* d_ws, size_t ws_size,
                              hipStream_t stream) {
    const float* x     = (const float*)d_in[0];
    const float* u     = (const float*)d_in[1];
    const int*   batch = (const int*)  d_in[2];
    const int*   hidx  = (const int*)  d_in[3];
    const int*   bh    = (const int*)  d_in[4];
    const float* W1 = (const float*)d_in[6];
    const float* b1 = (const float*)d_in[7];
    const float* W2 = (const float*)d_in[8];
    const float* b2 = (const float*)d_in[9];
    const float* W3 = (const float*)d_in[10];
    const float* b3 = (const float*)d_in[11];
    const float* Wg = (const float*)d_in[12];
    const float* V1 = (const float*)d_in[13];
    const float* c1 = (const float*)d_in[14];
    const float* V2 = (const float*)d_in[15];
    const float* c2 = (const float*)d_in[16];
    const float* V3 = (const float*)d_in[17];
    const float* c3 = (const float*)d_in[18];

    const int N = in_sizes[0] / 6;
    const int G = in_sizes[1] / 4;
    const int E = in_sizes[4];

    // ws layout (R17: Xh eliminated)
    char* ws = (char*)d_ws;
    size_t off = 0;
    u16* hb = (u16*)(ws + off);            off += (size_t)N * 64 * 2;
    int* seg_start = (int*)(ws + off);     off += ((size_t)G + 1) * 4;
    off = (off + 255) & ~(size_t)255;
    u16* SWZ = (u16*)(ws + off);           off += 16384 * 2;
    float* Sinv = (float*)(ws + off);      off += (size_t)G * 64 * 4;
    float* out = (float*)d_out;

    const int SB = (G + 256) / 256;
    const int NB = (N + 15) / 16;
    prep_mlp_kernel<<<32 + SB + NB, 256, 0, stream>>>(
        x, u, batch, W1, b1, W2, b2, W3, b3, hb, N,
        Wg, V1, V2, SWZ, bh, E, G, seg_start, SB);
    gather_stats_kernel<<<G, 256, 0, stream>>>(hb, hidx, seg_start, Sinv, out, E);
    mfma_seg_kernel<<<G, 256, 0, stream>>>(
        hb, hidx, seg_start, SWZ, Sinv, c1, c2, V3, c3, out, E);
}